// Round 1
// baseline (97.016 us; speedup 1.0000x reference)
//
#include <hip/hip_runtime.h>

// Haar DWT2D forward: (8,32,512,512) f32 -> (8,128,257,257) f32
// out[b, k*32+c, i, j] = sum_t filt[k,t] * win_t, where the 2x2 window for
// output (i,j) is input rows {2i-1, 2i}, cols {2j-1, 2j} with reflect-1 pad
// (row -1 -> 1, row 512 -> 510; same for cols).

constexpr int H_IN  = 512;
constexpr int W_IN  = 512;
constexpr int H_OUT = 257;
constexpr int W_OUT = 257;
constexpr int C_IN  = 32;
constexpr int B_SZ  = 8;
constexpr long long PLANE_OUT = (long long)H_OUT * W_OUT;   // 66049
constexpr long long PLANE_IN  = (long long)H_IN * W_IN;     // 262144
constexpr long long TOTAL     = (long long)B_SZ * C_IN * PLANE_OUT; // 16,908,544

__global__ __launch_bounds__(256)
void dwt2d_haar_kernel(const float* __restrict__ x,
                       const float* __restrict__ filt,
                       float* __restrict__ out) {
    long long idx = (long long)blockIdx.x * 256 + threadIdx.x;
    if (idx >= TOTAL) return;

    int bc  = (int)(idx / PLANE_OUT);           // 0..255 (b*32 + c)
    int rem = (int)(idx - (long long)bc * PLANE_OUT);
    int i   = rem / W_OUT;
    int j   = rem - i * W_OUT;

    // reflect-padded window coordinates in the input image
    int r0 = 2 * i - 1; r0 = (r0 < 0)      ? 1          : r0;
    int r1 = 2 * i;     r1 = (r1 >= H_IN)  ? (H_IN - 2) : r1;
    int c0 = 2 * j - 1; c0 = (c0 < 0)      ? 1          : c0;
    int c1 = 2 * j;     c1 = (c1 >= W_IN)  ? (W_IN - 2) : c1;

    const float* xp = x + (long long)bc * PLANE_IN;
    float a = xp[(long long)r0 * W_IN + c0];   // x00
    float b = xp[(long long)r0 * W_IN + c1];   // x01
    float c = xp[(long long)r1 * W_IN + c0];   // x10
    float d = xp[(long long)r1 * W_IN + c1];   // x11

    // filters: 4 subbands x 4 taps, row-major (uniform loads -> s_load)
    float F[16];
#pragma unroll
    for (int t = 0; t < 16; ++t) F[t] = filt[t];

    int bb = bc >> 5;        // batch
    int cc = bc & 31;        // channel
    // out channel = k*32 + cc, batch stride = 128 planes
    long long obase = ((long long)(bb * 128 + cc)) * PLANE_OUT + rem;
#pragma unroll
    for (int k = 0; k < 4; ++k) {
        float v = F[4 * k + 0] * a + F[4 * k + 1] * b
                + F[4 * k + 2] * c + F[4 * k + 3] * d;
        out[obase + (long long)(k * 32) * PLANE_OUT] = v;
    }
}

extern "C" void kernel_launch(void* const* d_in, const int* in_sizes, int n_in,
                              void* d_out, int out_size, void* d_ws, size_t ws_size,
                              hipStream_t stream) {
    const float* x    = (const float*)d_in[0];
    const float* filt = (const float*)d_in[1];
    float*       out  = (float*)d_out;

    long long grid = (TOTAL + 255) / 256;   // 66049
    dwt2d_haar_kernel<<<(unsigned)grid, 256, 0, stream>>>(x, filt, out);
}

// Round 2
// 94.517 us; speedup vs baseline: 1.0264x; 1.0264x over previous
//
#include <hip/hip_runtime.h>

// Haar DWT2D forward: (8,32,512,512) f32 -> (8,128,257,257) f32
// out[b, k*32+c, i, j] = sum_t filt[k,t] * win_t; 2x2 window for output (i,j)
// is input rows {2i-1, 2i}, cols {2j-1, 2j}, reflect-1 (-1 -> 1, 512 -> 510).
//
// One block per (bc, output row i). Stage the two input rows into LDS via
// coalesced float4 loads, compute all 257 outputs x 4 subbands, stream the
// results out with nontemporal stores.

constexpr int H_IN  = 512;
constexpr int W_IN  = 512;
constexpr int H_OUT = 257;
constexpr int W_OUT = 257;
constexpr long long PLANE_OUT = (long long)H_OUT * W_OUT;   // 66049
constexpr long long PLANE_IN  = (long long)H_IN * W_IN;     // 262144

__global__ __launch_bounds__(256)
void dwt2d_haar_rows(const float* __restrict__ x,
                     const float* __restrict__ filt,
                     float* __restrict__ out) {
    const int i  = blockIdx.x;   // output row 0..256
    const int bc = blockIdx.y;   // b*32 + c, 0..255
    const int t  = threadIdx.x;  // 0..255

    __shared__ float row0[W_IN];
    __shared__ float row1[W_IN];

    int r0 = 2 * i - 1; if (r0 < 0)     r0 = 1;           // reflect top
    int r1 = 2 * i;     if (r1 >= H_IN) r1 = H_IN - 2;    // reflect bottom

    const float* xp = x + (long long)bc * PLANE_IN;

    // Stage two rows: threads 0..127 -> row0, 128..255 -> row1, float4 each.
    {
        const int half = t >> 7;           // 0 or 1
        const int lane = (t & 127) << 2;   // col 0,4,...,508
        const float* src = xp + (long long)(half ? r1 : r0) * W_IN + lane;
        float4 v = *reinterpret_cast<const float4*>(src);
        float* dst = (half ? row1 : row0) + lane;
        dst[0] = v.x; dst[1] = v.y; dst[2] = v.z; dst[3] = v.w;
    }
    __syncthreads();

    // Filters: 4 subbands x 4 taps (uniform scalar loads).
    float F[16];
#pragma unroll
    for (int k = 0; k < 16; ++k) F[k] = filt[k];

    const int bb = bc >> 5;   // batch
    const int cc = bc & 31;   // channel
    const long long obase = (long long)(bb * 128 + cc) * PLANE_OUT
                          + (long long)i * W_OUT;

    // Main outputs: j = t (0..255)
    {
        int c0 = 2 * t - 1; if (c0 < 0) c0 = 1;   // reflect left
        int c1 = 2 * t;                            // <= 510, in range
        float a = row0[c0], b = row0[c1];
        float c = row1[c0], d = row1[c1];
#pragma unroll
        for (int k = 0; k < 4; ++k) {
            float v = F[4*k+0] * a + F[4*k+1] * b + F[4*k+2] * c + F[4*k+3] * d;
            __builtin_nontemporal_store(v, &out[obase + (long long)(k * 32) * PLANE_OUT + t]);
        }
    }
    // Extra output j = 256 (c0 = 511, c1 = 512 -> reflect 510), one thread.
    if (t == 0) {
        float a = row0[511], b = row0[510];
        float c = row1[511], d = row1[510];
#pragma unroll
        for (int k = 0; k < 4; ++k) {
            float v = F[4*k+0] * a + F[4*k+1] * b + F[4*k+2] * c + F[4*k+3] * d;
            __builtin_nontemporal_store(v, &out[obase + (long long)(k * 32) * PLANE_OUT + 256]);
        }
    }
}

extern "C" void kernel_launch(void* const* d_in, const int* in_sizes, int n_in,
                              void* d_out, int out_size, void* d_ws, size_t ws_size,
                              hipStream_t stream) {
    const float* x    = (const float*)d_in[0];
    const float* filt = (const float*)d_in[1];
    float*       out  = (float*)d_out;

    dim3 grid(H_OUT, 256);   // 257 rows x (8*32) planes
    dwt2d_haar_rows<<<grid, 256, 0, stream>>>(x, filt, out);
}